// Round 4
// baseline (299.662 us; speedup 1.0000x reference)
//
#include <hip/hip_runtime.h>
#include <hip/hip_bf16.h>

#define C_ 8
#define B_ 32
#define G_ 2048
#define S_ 32
#define L_ 3

#define NBLK 256
#define NTHR 1024

// ws float offsets
#define OFF_BUF0 0                    // [C][G][B] unnormalized R (for gathers)
#define OFF_MAX  524288               // cmax slots (t*8+c)*16
#define OFF_GMAX (OFF_MAX + 512)      // gmax slots t*16
#define OFF_CNT  (OFF_MAX + 576)      // 16 uints (grid barrier counters)
#define OFF_XT   (OFF_MAX + 640)      // xT [G][B] = transpose of x
#define ZERO_FLOATS 640

__device__ __forceinline__ void atomicMaxPos(float* a, float v) {
    // all values >= 0, so uint compare == float compare
    atomicMax((unsigned*)a, __float_as_uint(v));
}

__device__ __forceinline__ void gridBarrier(unsigned* cnt, int idx) {
    __syncthreads();
    if (threadIdx.x == 0) {
        __threadfence();                         // release
        atomicAdd(&cnt[idx], 1u);
        while (__hip_atomic_load(&cnt[idx], __ATOMIC_RELAXED,
                                 __HIP_MEMORY_SCOPE_AGENT) < (unsigned)NBLK)
            __builtin_amdgcn_s_sleep(2);
        __threadfence();                         // acquire
    }
    __syncthreads();
}

__device__ __forceinline__ float softor32(const float* __restrict__ Rb,
                                          const int4* __restrict__ p,
                                          float sc3) {
    float body[S_];
#pragma unroll
    for (int q = 0; q < 8; ++q) {                // 4 substitutions per group
        const int4 a = p[3 * q + 0];
        const int4 d = p[3 * q + 1];
        const int4 e = p[3 * q + 2];
        body[4 * q + 0] = Rb[a.x << 5] * Rb[a.y << 5] * Rb[a.z << 5] * sc3;
        body[4 * q + 1] = Rb[a.w << 5] * Rb[d.x << 5] * Rb[d.y << 5] * sc3;
        body[4 * q + 2] = Rb[d.z << 5] * Rb[d.w << 5] * Rb[e.x << 5] * sc3;
        body[4 * q + 3] = Rb[e.y << 5] * Rb[e.z << 5] * Rb[e.w << 5] * sc3;
    }
    float mx = body[0];
#pragma unroll
    for (int s = 1; s < S_; ++s) mx = fmaxf(mx, body[s]);
    float sum = 0.0f;
#pragma unroll
    for (int s = 0; s < S_; ++s) sum += __expf((body[s] - mx) * 100.0f);
    return mx + 0.01f * __logf(sum);
}

__global__ __launch_bounds__(NTHR, 4) void k_fused(const float* __restrict__ x,
                                                   const int* __restrict__ I,
                                                   float* __restrict__ out,
                                                   float* __restrict__ ws) {
    __shared__ int sIdx[64 * 96];       // this block's 64 rows x 96 indices (24.6 KB)
    __shared__ float sT[32 * 65];       // transpose tile, stride 65 (conflict-free)
    __shared__ float sRed[16];

    float* buf0 = ws + OFF_BUF0;
    float* cmax = ws + OFF_MAX;
    float* gmax = ws + OFF_GMAX;
    unsigned* cnt = (unsigned*)(ws + OFF_CNT);
    float* xT = ws + OFF_XT;

    const int tid = threadIdx.x;
    const int bid = blockIdx.x;
    const int lane = tid & 63;
    const int wv = tid >> 6;
    const int b = tid & 31;
    const int rowloc = tid >> 5;        // 0..31
    const int c = bid >> 5;             // 32 blocks per clause, all rows same clause
    const int r0 = bid * 64;            // block's first global row
    const int item0 = bid * 2048 + tid; // = (r0 + rowloc)*32 + b
    const int item1 = item0 + 1024;     // = (r0 + rowloc + 32)*32 + b

    // ---- stage 64 index rows (valid for all steps) ----
    {
        const int* Ib = I + r0 * (S_ * L_);
#pragma unroll
        for (int k = 0; k < 6; ++k) sIdx[tid + 1024 * k] = Ib[tid + 1024 * k];
    }

    // ---- init: xT[g][b] = x[b][g] (first 64 blocks, 32 g's each) ----
    if (bid < 64) {
        const int g0 = bid * 32;
        sT[(tid & 31) * 65 + (tid >> 5)] = x[(tid >> 5) * G_ + g0 + (tid & 31)];
        __syncthreads();
        xT[(g0 + rowloc) * B_ + b] = sT[rowloc * 65 + b];
    }
    gridBarrier(cnt, 0);                // also publishes sIdx within block

    const int4* idx0 = (const int4*)(sIdx + rowloc * 96);
    const int4* idx1 = (const int4*)(sIdx + (rowloc + 32) * 96);

    float acc0 = xT[item0 & (G_ * B_ - 1)];
    float acc1 = xT[item1 & (G_ * B_ - 1)];

#pragma unroll 1
    for (int t = 0; t < 4; ++t) {
        const float* Rc = (t == 0) ? xT : (buf0 + c * (G_ * B_));
        const float* Rb = Rc + b;
        const float gm = (t == 0) ? 0.0f : gmax[(t - 1) * 16];
        const float sc = (gm > 1.0f) ? (1.0f / gm) : 1.0f;
        const float sc3 = sc * sc * sc;

        // ---- clause phase ----
        const float lse0 = softor32(Rb, idx0, sc3);
        const float lse1 = softor32(Rb, idx1, sc3);

        // ---- per-clause max (block is single-clause) ----
        float m = fmaxf(lse0, lse1);
#pragma unroll
        for (int o = 32; o; o >>= 1) m = fmaxf(m, __shfl_xor(m, o, 64));
        if (lane == 0) sRed[wv] = m;
        __syncthreads();
        if (tid == 0) {
            float a = sRed[0];
#pragma unroll
            for (int k = 1; k < 16; ++k) a = fmaxf(a, sRed[k]);
            atomicMaxPos(&cmax[(t * 8 + c) * 16], a);
        }
        gridBarrier(cnt, 1 + 2 * t);

        // ---- combine in registers ----
        const float cmv = cmax[(t * 8 + c) * 16];
        const float scr = (cmv > 1.0f) ? (1.0f / cmv) : 1.0f;
        {
            const float Rn = acc0 * sc, rn = lse0 * scr;
            const float M = fmaxf(Rn, rn), mn = fminf(Rn, rn);
            acc0 = M + 0.01f * __logf(1.0f + __expf((mn - M) * 100.0f));
        }
        {
            const float Rn = acc1 * sc, rn = lse1 * scr;
            const float M = fmaxf(Rn, rn), mn = fminf(Rn, rn);
            acc1 = M + 0.01f * __logf(1.0f + __expf((mn - M) * 100.0f));
        }
        if (t < 3) { buf0[item0] = acc0; buf0[item1] = acc1; }

        // ---- global max ----
        float mm = fmaxf(acc0, acc1);
#pragma unroll
        for (int o = 32; o; o >>= 1) mm = fmaxf(mm, __shfl_xor(mm, o, 64));
        if (lane == 0) sRed[wv] = mm;
        __syncthreads();
        if (tid == 0) {
            float a = sRed[0];
#pragma unroll
            for (int k = 1; k < 16; ++k) a = fmaxf(a, sRed[k]);
            atomicMaxPos(&gmax[t * 16], a);
        }
        gridBarrier(cnt, 2 + 2 * t);
    }

    // ---- out: registers -> LDS transpose -> [C][B][G] with final scale ----
    const float gfin = gmax[3 * 16];
    const float scf = (gfin > 1.0f) ? (1.0f / gfin) : 1.0f;
    sT[b * 65 + rowloc] = acc0 * scf;
    sT[b * 65 + rowloc + 32] = acc1 * scf;
    __syncthreads();
    {
        const int g0 = (bid & 31) * 64;
#pragma unroll
        for (int k = 0; k < 2; ++k) {
            const int j = tid + k * 1024;
            const int bb = j >> 6, gg = j & 63;
            out[(c * B_ + bb) * G_ + g0 + gg] = sT[bb * 65 + gg];  // coalesced
        }
    }
}

extern "C" void kernel_launch(void* const* d_in, const int* in_sizes, int n_in,
                              void* d_out, int out_size, void* d_ws, size_t ws_size,
                              hipStream_t stream) {
    const float* x = (const float*)d_in[0];
    const int* I = (const int*)d_in[1];
    float* out = (float*)d_out;
    float* ws = (float*)d_ws;

    hipMemsetAsync(ws + OFF_MAX, 0, ZERO_FLOATS * sizeof(float), stream);

    void* args[] = {(void*)&x, (void*)&I, (void*)&out, (void*)&ws};
    hipLaunchCooperativeKernel((const void*)k_fused, dim3(NBLK), dim3(NTHR),
                               args, 0, stream);
}

// Round 5
// 113.687 us; speedup vs baseline: 2.6359x; 2.6359x over previous
//
#include <hip/hip_runtime.h>
#include <hip/hip_bf16.h>

#define C_ 8
#define B_ 32
#define G_ 2048
#define S_ 32
#define L_ 3
#define GB_ (G_ * B_)                 // 65536 items per clause

// ws float offsets
#define OFF_BUF0 0                     // [C][G][B] unnormalized R (gather source)
#define OFF_BUF1 524288                // [C][G][B] clause lse r
#define OFF_MAX  1048576               // cmax slots: (t*8+c)*16 -> 512 floats
#define OFF_GMAX (OFF_MAX + 512)       // gmax slots: t*16 -> 64 floats
#define OFF_XT   (OFF_MAX + 640)       // xT [G][B]
#define ZERO_FLOATS 576

__device__ __forceinline__ void atomicMaxPos(float* a, float v) {
    // all values >= 0, so uint compare == float compare
    atomicMax((unsigned*)a, __float_as_uint(v));
}

// ---- build xT[g][b] = x[b][g]; zero the max slots ----
__global__ __launch_bounds__(1024) void k_init(const float* __restrict__ x,
                                               float* __restrict__ xT,
                                               float* __restrict__ maxs) {
    __shared__ float sT[32 * 33];
    const int tid = threadIdx.x, bid = blockIdx.x;    // 64 blocks x 1024
    const int g0 = bid * 32;
    sT[(tid & 31) * 33 + (tid >> 5)] = x[(tid >> 5) * G_ + g0 + (tid & 31)];
    __syncthreads();
    xT[(g0 + (tid >> 5)) * B_ + (tid & 31)] = sT[(tid >> 5) * 33 + (tid & 31)];
    if (bid == 0 && tid < ZERO_FLOATS) maxs[tid] = 0.0f;
}

// ---- clause: r = softor_S(prod_L R[c, I, b]), online LSE, batched gathers ----
__global__ __launch_bounds__(256, 8) void k_clause(const float* __restrict__ Rbase,
                                                   int cstride,                 // 0 at t=0
                                                   const int* __restrict__ I,
                                                   float* __restrict__ r_out,   // buf1
                                                   const float* __restrict__ gmax_prev,
                                                   float* __restrict__ cmax_step) {
    __shared__ int sIdx[8 * 96];        // 3 KB: 8 rows x 96 indices
    __shared__ float sRed[4];

    const int tid = threadIdx.x;
    const int bid = blockIdx.x;         // 2048 blocks, 8 rows each
    const int c = bid >> 8;             // 256 blocks per clause
    const int r0 = bid * 8;

    {   // stage indices (coalesced)
        const int* Ib = I + r0 * 96;
#pragma unroll
        for (int k = 0; k < 3; ++k) sIdx[tid + 256 * k] = Ib[tid + 256 * k];
    }
    __syncthreads();

    const float gm = gmax_prev ? gmax_prev[0] : 0.0f;
    const float sc = (gm > 1.0f) ? (1.0f / gm) : 1.0f;
    const float sc3 = sc * sc * sc;

    const int b = tid & 31;
    const int rl = tid >> 5;            // 0..7
    const float* Rb = Rbase + c * cstride + b;
    const int4* p = (const int4*)(sIdx + rl * 96);

    float mx = -1e30f, sum = 0.0f;
#pragma unroll
    for (int ch = 0; ch < 4; ++ch) {    // 8 substitutions per chunk, 24 batched loads
        const int4 q0 = p[ch * 6 + 0], q1 = p[ch * 6 + 1], q2 = p[ch * 6 + 2];
        const int4 q3 = p[ch * 6 + 3], q4 = p[ch * 6 + 4], q5 = p[ch * 6 + 5];
        float v[24];
        v[0]  = Rb[q0.x << 5]; v[1]  = Rb[q0.y << 5]; v[2]  = Rb[q0.z << 5];
        v[3]  = Rb[q0.w << 5]; v[4]  = Rb[q1.x << 5]; v[5]  = Rb[q1.y << 5];
        v[6]  = Rb[q1.z << 5]; v[7]  = Rb[q1.w << 5]; v[8]  = Rb[q2.x << 5];
        v[9]  = Rb[q2.y << 5]; v[10] = Rb[q2.z << 5]; v[11] = Rb[q2.w << 5];
        v[12] = Rb[q3.x << 5]; v[13] = Rb[q3.y << 5]; v[14] = Rb[q3.z << 5];
        v[15] = Rb[q3.w << 5]; v[16] = Rb[q4.x << 5]; v[17] = Rb[q4.y << 5];
        v[18] = Rb[q4.z << 5]; v[19] = Rb[q4.w << 5]; v[20] = Rb[q5.x << 5];
        v[21] = Rb[q5.y << 5]; v[22] = Rb[q5.z << 5]; v[23] = Rb[q5.w << 5];
        float bo[8];
#pragma unroll
        for (int s = 0; s < 8; ++s) bo[s] = v[3 * s] * v[3 * s + 1] * v[3 * s + 2] * sc3;
        float cm = fmaxf(fmaxf(fmaxf(bo[0], bo[1]), fmaxf(bo[2], bo[3])),
                         fmaxf(fmaxf(bo[4], bo[5]), fmaxf(bo[6], bo[7])));
        const float nmx = fmaxf(mx, cm);
        float ps = 0.0f;
#pragma unroll
        for (int s = 0; s < 8; ++s) ps += __expf((bo[s] - nmx) * 100.0f);
        sum = sum * __expf((mx - nmx) * 100.0f) + ps;
        mx = nmx;
    }
    const float lse = mx + 0.01f * __logf(sum);

    r_out[bid * 256 + tid] = lse;

    // per-clause max partials -> atomic
    float m = lse;
#pragma unroll
    for (int o = 32; o; o >>= 1) m = fmaxf(m, __shfl_xor(m, o, 64));
    const int lane = tid & 63, wv = tid >> 6;
    if (lane == 0) sRed[wv] = m;
    __syncthreads();
    if (tid == 0) {
        float a = fmaxf(fmaxf(sRed[0], sRed[1]), fmaxf(sRed[2], sRed[3]));
        atomicMaxPos(&cmax_step[c * 16], a);
    }
}

// ---- combine: acc = softor2(Rold*sc, r*scr), float4, gmax atomic ----
__global__ __launch_bounds__(256, 8) void k_combine(const float* __restrict__ Rold,
                                                    int mask,                     // 65535 at t=0
                                                    const float* __restrict__ r_in,
                                                    float* __restrict__ Rnew,     // buf0
                                                    const float* __restrict__ gmax_prev,
                                                    const float* __restrict__ cmax_step,
                                                    float* __restrict__ gmax_out) {
    __shared__ float sRed[4];
    const int tid = threadIdx.x;
    const int i4 = (blockIdx.x * 256 + tid) * 4;     // 512 blocks cover 524288 items
    const int c = i4 >> 16;

    const float gm = gmax_prev ? gmax_prev[0] : 0.0f;
    const float sc = (gm > 1.0f) ? (1.0f / gm) : 1.0f;
    const float cmv = cmax_step[c * 16];
    const float scr = (cmv > 1.0f) ? (1.0f / cmv) : 1.0f;

    const float4 Ro = *(const float4*)(Rold + (i4 & mask));
    const float4 rv = *(const float4*)(r_in + i4);
    float4 o;
    {
        float Rn = Ro.x * sc, rn = rv.x * scr;
        float M = fmaxf(Rn, rn), mn = fminf(Rn, rn);
        o.x = M + 0.01f * __logf(1.0f + __expf((mn - M) * 100.0f));
    }
    {
        float Rn = Ro.y * sc, rn = rv.y * scr;
        float M = fmaxf(Rn, rn), mn = fminf(Rn, rn);
        o.y = M + 0.01f * __logf(1.0f + __expf((mn - M) * 100.0f));
    }
    {
        float Rn = Ro.z * sc, rn = rv.z * scr;
        float M = fmaxf(Rn, rn), mn = fminf(Rn, rn);
        o.z = M + 0.01f * __logf(1.0f + __expf((mn - M) * 100.0f));
    }
    {
        float Rn = Ro.w * sc, rn = rv.w * scr;
        float M = fmaxf(Rn, rn), mn = fminf(Rn, rn);
        o.w = M + 0.01f * __logf(1.0f + __expf((mn - M) * 100.0f));
    }
    *(float4*)(Rnew + i4) = o;

    float mm = fmaxf(fmaxf(o.x, o.y), fmaxf(o.z, o.w));
#pragma unroll
    for (int off = 32; off; off >>= 1) mm = fmaxf(mm, __shfl_xor(mm, off, 64));
    const int lane = tid & 63, wv = tid >> 6;
    if (lane == 0) sRed[wv] = mm;
    __syncthreads();
    if (tid == 0) {
        float a = fmaxf(fmaxf(sRed[0], sRed[1]), fmaxf(sRed[2], sRed[3]));
        atomicMaxPos(gmax_out, a);
    }
}

// ---- out: transpose [C][G][B] -> [C][B][G] with final global-max scale ----
__global__ __launch_bounds__(256) void k_out(const float* __restrict__ buf0,
                                             const float* __restrict__ gmaxslot,
                                             float* __restrict__ out) {
    __shared__ float sT[64 * 33];
    const int bid = blockIdx.x;        // 256 blocks
    const int c = bid >> 5;
    const int g0 = (bid & 31) << 6;
    const int tid = threadIdx.x;

    const float gm = gmaxslot[0];
    const float sc = (gm > 1.0f) ? (1.0f / gm) : 1.0f;

    const float* src = buf0 + (c * G_ + g0) * B_;
#pragma unroll
    for (int k = 0; k < 8; ++k) {
        int j = tid + 256 * k;
        sT[(j >> 5) * 33 + (j & 31)] = src[j] * sc;
    }
    __syncthreads();
#pragma unroll
    for (int k = 0; k < 8; ++k) {
        int j = tid + 256 * k;
        int b = j >> 6, gg = j & 63;
        out[(c * B_ + b) * G_ + g0 + gg] = sT[gg * 33 + b];
    }
}

extern "C" void kernel_launch(void* const* d_in, const int* in_sizes, int n_in,
                              void* d_out, int out_size, void* d_ws, size_t ws_size,
                              hipStream_t stream) {
    const float* x = (const float*)d_in[0];
    const int* I = (const int*)d_in[1];
    float* out = (float*)d_out;
    float* ws = (float*)d_ws;

    float* buf0 = ws + OFF_BUF0;
    float* buf1 = ws + OFF_BUF1;
    float* maxs = ws + OFF_MAX;         // cmax slots
    float* gmax = ws + OFF_GMAX;        // gmax slots
    float* xT = ws + OFF_XT;

    k_init<<<64, 1024, 0, stream>>>(x, xT, maxs);

    for (int t = 0; t < 4; ++t) {
        const float* Rsrc = (t == 0) ? xT : buf0;
        const int cs = (t == 0) ? 0 : GB_;
        const float* gprev = (t == 0) ? nullptr : (gmax + (t - 1) * 16);
        float* cstep = maxs + t * 128;
        const int mask = (t == 0) ? (GB_ - 1) : 0x7FFFFFFF;

        k_clause<<<2048, 256, 0, stream>>>(Rsrc, cs, I, buf1, gprev, cstep);
        k_combine<<<512, 256, 0, stream>>>(Rsrc, mask, buf1, buf0, gprev, cstep,
                                           gmax + t * 16);
    }

    k_out<<<256, 256, 0, stream>>>(buf0, gmax + 48, out);
}